// Round 4
// baseline (820.349 us; speedup 1.0000x reference)
//
#include <hip/hip_runtime.h>
#include <hip/hip_bf16.h>
#include <stdint.h>

#define N_NODES 262144
#define N_EDGES 524288
#define EMB 256
#define LN_EPS 1e-5f
#define CSR_CAP 1024

typedef unsigned short u16;
typedef unsigned int u32;
typedef __bf16 bf16_t;
typedef __bf16 bf16x8 __attribute__((ext_vector_type(8)));
typedef float f32x4 __attribute__((ext_vector_type(4)));

__device__ __forceinline__ u16 f2bf(float f) {
    u32 u = __float_as_uint(f);
    u32 r = u + 0x7fffu + ((u >> 16) & 1u);
    return (u16)(r >> 16);
}
__device__ __forceinline__ float bf2f(u16 b) { return __uint_as_float(((u32)b) << 16); }
__device__ __forceinline__ float lo16(u32 x) { return __uint_as_float(x << 16); }
__device__ __forceinline__ float hi16(u32 x) { return __uint_as_float(x & 0xffff0000u); }

__device__ __forceinline__ void async_copy16(void* lds, const void* g) {
    __builtin_amdgcn_global_load_lds(
        (const __attribute__((address_space(1))) u32*)g,
        (__attribute__((address_space(3))) u32*)lds, 16, 0, 0);
}

// ---------- convert 4 weight matrices fp32 -> bf16 into ws ----------
__global__ __launch_bounds__(256) void convert_w_kernel(
    const float* __restrict__ a, const float* __restrict__ b,
    const float* __restrict__ c, const float* __restrict__ d,
    u16* __restrict__ out)
{
    int seg = blockIdx.x >> 6;       // 0..3
    int blk = blockIdx.x & 63;       // 0..63
    const float* src = (seg == 0) ? a : (seg == 1) ? b : (seg == 2) ? c : d;
    int off = blk * 1024 + threadIdx.x * 4;
    float4 v = *(const float4*)(src + off);
    uint2 o;
    o.x = (u32)f2bf(v.x) | ((u32)f2bf(v.y) << 16);
    o.y = (u32)f2bf(v.z) | ((u32)f2bf(v.w) << 16);
    *(uint2*)(out + seg * 65536 + off) = o;
}

// ---------- embed + layernorm: one wave per row (fp32 inputs -> bf16 h0) ----------
__global__ __launch_bounds__(256) void embed_ln_kernel(
    const int* __restrict__ node_emb, const int* __restrict__ pos,
    const float* __restrict__ node_tab, const float* __restrict__ pos_tab,
    const float* __restrict__ g_emb, const float* __restrict__ b_emb,
    u16* __restrict__ h0)
{
    const int wid = threadIdx.x >> 6, lane = threadIdx.x & 63;
    const int row = blockIdx.x * 4 + wid;
    const int idx = node_emb[row];
    const int p = pos[row];
    float4 ra = *(const float4*)(node_tab + (size_t)idx * EMB + lane * 4);
    float4 rb = *(const float4*)(pos_tab + (size_t)p * EMB + lane * 4);
    float v0 = ra.x * 16.f + rb.x;
    float v1 = ra.y * 16.f + rb.y;
    float v2 = ra.z * 16.f + rb.z;
    float v3 = ra.w * 16.f + rb.w;
    float s = v0 + v1 + v2 + v3;
    float sq = v0 * v0 + v1 * v1 + v2 * v2 + v3 * v3;
    #pragma unroll
    for (int m = 1; m < 64; m <<= 1) { s += __shfl_xor(s, m); sq += __shfl_xor(sq, m); }
    float mean = s * (1.f / 256.f);
    float var = sq * (1.f / 256.f) - mean * mean;
    float rstd = rsqrtf(var + LN_EPS);
    float4 rg = *(const float4*)(g_emb + lane * 4);
    float4 rbt = *(const float4*)(b_emb + lane * 4);
    float o0 = (v0 - mean) * rstd * rg.x + rbt.x;
    float o1 = (v1 - mean) * rstd * rg.y + rbt.y;
    float o2 = (v2 - mean) * rstd * rg.z + rbt.z;
    float o3 = (v3 - mean) * rstd * rg.w + rbt.w;
    uint2 out;
    out.x = (u32)f2bf(o0) | ((u32)f2bf(o1) << 16);
    out.y = (u32)f2bf(o2) | ((u32)f2bf(o3) << 16);
    *(uint2*)(h0 + (size_t)row * EMB + lane * 4) = out;
}

// ---------- CSR build ----------
__global__ __launch_bounds__(256) void hist_kernel(const int* __restrict__ dst, int* __restrict__ deg) {
    int e = blockIdx.x * 256 + threadIdx.x;
    atomicAdd(&deg[dst[e]], 1);
}

__global__ __launch_bounds__(1024) void scan1_kernel(const int* __restrict__ deg,
                                                     int* __restrict__ incl, int* __restrict__ bsum) {
    __shared__ int tmp[1024];
    int t = threadIdx.x, g = blockIdx.x * 1024 + t;
    tmp[t] = deg[g];
    __syncthreads();
    for (int off = 1; off < 1024; off <<= 1) {
        int x = (t >= off) ? tmp[t - off] : 0;
        __syncthreads();
        tmp[t] += x;
        __syncthreads();
    }
    incl[g] = tmp[t];
    if (t == 1023) bsum[blockIdx.x] = tmp[t];
}

__global__ __launch_bounds__(256) void scan2_kernel(const int* __restrict__ bsum, int* __restrict__ boff) {
    __shared__ int tmp[256];
    int t = threadIdx.x;
    int own = bsum[t];
    tmp[t] = own;
    __syncthreads();
    for (int off = 1; off < 256; off <<= 1) {
        int x = (t >= off) ? tmp[t - off] : 0;
        __syncthreads();
        tmp[t] += x;
        __syncthreads();
    }
    boff[t] = tmp[t] - own;
}

__global__ __launch_bounds__(256) void scan3_kernel(const int* __restrict__ incl, const int* __restrict__ deg,
                                                    const int* __restrict__ boff,
                                                    int* __restrict__ rowstart, int* __restrict__ cursor) {
    int g = blockIdx.x * 256 + threadIdx.x;
    int v = incl[g] - deg[g] + boff[g >> 10];
    rowstart[g] = v;
    cursor[g] = v;
    if (g == N_NODES - 1) rowstart[N_NODES] = N_EDGES;   // sentinel
}

__global__ __launch_bounds__(256) void scatter_kernel(const int* __restrict__ src, const int* __restrict__ dst,
                                                      int* __restrict__ cursor, int* __restrict__ csr) {
    int e = blockIdx.x * 256 + threadIdx.x;
    int slot = atomicAdd(&cursor[dst[e]], 1);
    csr[slot] = src[e];
}

// ---------- fused gather + GEMM: relu([segsum(h)|h] @ [Wl|Wr]^T + bl) + h, then LayerNorm ----------
// v5 (this round):
//  - residual read from LDS: aggA slices 0..3 still hold the staged self-rows
//    Hin[m0..m0+64)[0..256) after the K-loop (stageH data, never overwritten) -> epilogue
//    reads them via the swizzle instead of 32 scalar global loads/lane (saves ~134 MB
//    logical reads + ~4M VMEM requests per layer, bit-identical values).
//  - gather dual-row interleave: both rows of a group issue their pair-loads in the same
//    iteration (8 uint4 in flight/lane instead of 4), halving the exposed latency chain.
//    Per-row even/odd dual accumulators keep the summation order bit-identical.
template<bool F32OUT>
__global__ __launch_bounds__(512, 4) void gemm_fused_kernel(
    const u16* __restrict__ Hin,
    const int* __restrict__ rowstart, const int* __restrict__ csr,
    const u16* __restrict__ Wl, const u16* __restrict__ Wr,
    const float* __restrict__ bias, const float* __restrict__ gam, const float* __restrict__ bet,
    u16* __restrict__ outb, float* __restrict__ outf)
{
    __shared__ alignas(16) u16 aggA[4 * 64 * 64];  // 32 KB: [slice][row][64], swizzled
    __shared__ alignas(16) u16 lB[256 * 64];       // 32 KB, single-buffered (L2-hot weights)
    __shared__ int ls_row[72];                     // rowstart[m0..m0+64]
    __shared__ int lcsr[CSR_CAP];                  // block's contiguous csr segment
    __shared__ float s_sum[64];
    __shared__ float s_sq[64];

    const int tid = threadIdx.x;
    const int wid = tid >> 6, lane = tid & 63;
    const int quad = lane >> 4, l16 = lane & 15;
    const int wrow = wid >> 2, wcol = wid & 3;
    const int m0 = blockIdx.x * 64;
    const int lsrc = ((lane & 7) ^ (lane >> 3)) * 8;   // inverse-swizzled source k-offset

    auto stageB = [&](int s) {
        const int k0 = s * 64;
        const u16* Bsrc = (k0 < 256) ? (Wl + k0) : (Wr + (k0 - 256));
        #pragma unroll
        for (int t = 0; t < 4; ++t) {
            int q = wid * 4 + t;
            int n = q * 8 + (lane >> 3);
            async_copy16((char*)lB + q * 1024, Bsrc + (size_t)n * EMB + lsrc);
        }
    };
    auto stageH = [&](int t) {          // h self-tile for k-step t (4..7) -> freed slice t-4
        int row = tid >> 3;             // 0..63
        int kg = (tid & 7) ^ (row & 7);
        async_copy16((char*)aggA + (t - 4) * 8192 + tid * 16,
                     Hin + (size_t)(m0 + row) * EMB + (t - 4) * 64 + kg * 8);
    };

    stageB(0);   // B(0) L2 latency hides under the gather phase

    // ---- phase 0: burst-load rowstart + csr segment into LDS ----
    const int beg_all = rowstart[m0];          // broadcast load
    const int end_all = rowstart[m0 + 64];     // broadcast load
    const int cnt = end_all - beg_all;
    if (tid < 65) ls_row[tid] = rowstart[m0 + tid];
    const int lim = (cnt < CSR_CAP) ? cnt : CSR_CAP;
    for (int e = tid; e < lim; e += 512) lcsr[e] = csr[beg_all + e];
    asm volatile("s_waitcnt lgkmcnt(0)\n\ts_barrier" ::: "memory");

    // ---- phase 1: gather segment-sum into aggA slices 0..3 (dual-row interleaved) ----
    {
        const int grp = tid >> 4, gl = tid & 15;   // 32 groups x 16 lanes; lane covers 16 cols
        const int r0 = grp * 2, r1 = r0 + 1;
        const int begr0 = ls_row[r0];
        const int endr0 = ls_row[r0 + 1];
        const int endr1 = ls_row[r1 + 1];
        // per-row dual even/odd accumulators: summation order bit-identical to v2-v4
        float A0[16] = {}, A1[16] = {};
        float B0[16] = {}, B1[16] = {};
        int j0 = begr0, j1 = endr0;    // row1 starts at ls_row[r1] == endr0
        while ((j0 + 1 < endr0) | (j1 + 1 < endr1)) {
            bool v0 = (j0 + 1 < endr0), v1 = (j1 + 1 < endr1);
            int s00, s01, s10, s11;
            uint4 q0, q1, q2, q3, p0, p1, p2, p3;
            if (v0) {
                int sl = j0 - beg_all;
                s00 = (sl < CSR_CAP) ? lcsr[sl] : csr[j0];
                s01 = (sl + 1 < CSR_CAP) ? lcsr[sl + 1] : csr[j0 + 1];
                const u16* pa = Hin + (size_t)s00 * EMB + gl * 16;
                const u16* pb = Hin + (size_t)s01 * EMB + gl * 16;
                q0 = *(const uint4*)pa; q2 = *(const uint4*)(pa + 8);
                q1 = *(const uint4*)pb; q3 = *(const uint4*)(pb + 8);
            }
            if (v1) {
                int sl = j1 - beg_all;
                s10 = (sl < CSR_CAP) ? lcsr[sl] : csr[j1];
                s11 = (sl + 1 < CSR_CAP) ? lcsr[sl + 1] : csr[j1 + 1];
                const u16* pa = Hin + (size_t)s10 * EMB + gl * 16;
                const u16* pb = Hin + (size_t)s11 * EMB + gl * 16;
                p0 = *(const uint4*)pa; p2 = *(const uint4*)(pa + 8);
                p1 = *(const uint4*)pb; p3 = *(const uint4*)(pb + 8);
            }
            if (v0) {
                A0[0]  += lo16(q0.x); A0[1]  += hi16(q0.x);
                A0[2]  += lo16(q0.y); A0[3]  += hi16(q0.y);
                A0[4]  += lo16(q0.z); A0[5]  += hi16(q0.z);
                A0[6]  += lo16(q0.w); A0[7]  += hi16(q0.w);
                A0[8]  += lo16(q2.x); A0[9]  += hi16(q2.x);
                A0[10] += lo16(q2.y); A0[11] += hi16(q2.y);
                A0[12] += lo16(q2.z); A0[13] += hi16(q2.z);
                A0[14] += lo16(q2.w); A0[15] += hi16(q2.w);
                A1[0]  += lo16(q1.x); A1[1]  += hi16(q1.x);
                A1[2]  += lo16(q1.y); A1[3]  += hi16(q1.y);
                A1[4]  += lo16(q1.z); A1[5]  += hi16(q1.z);
                A1[6]  += lo16(q1.w); A1[7]  += hi16(q1.w);
                A1[8]  += lo16(q3.x); A1[9]  += hi16(q3.x);
                A1[10] += lo16(q3.y); A1[11] += hi16(q3.y);
                A1[12] += lo16(q3.z); A1[13] += hi16(q3.z);
                A1[14] += lo16(q3.w); A1[15] += hi16(q3.w);
                j0 += 2;
            }
            if (v1) {
                B0[0]  += lo16(p0.x); B0[1]  += hi16(p0.x);
                B0[2]  += lo16(p0.y); B0[3]  += hi16(p0.y);
                B0[4]  += lo16(p0.z); B0[5]  += hi16(p0.z);
                B0[6]  += lo16(p0.w); B0[7]  += hi16(p0.w);
                B0[8]  += lo16(p2.x); B0[9]  += hi16(p2.x);
                B0[10] += lo16(p2.y); B0[11] += hi16(p2.y);
                B0[12] += lo16(p2.z); B0[13] += hi16(p2.z);
                B0[14] += lo16(p2.w); B0[15] += hi16(p2.w);
                B1[0]  += lo16(p1.x); B1[1]  += hi16(p1.x);
                B1[2]  += lo16(p1.y); B1[3]  += hi16(p1.y);
                B1[4]  += lo16(p1.z); B1[5]  += hi16(p1.z);
                B1[6]  += lo16(p1.w); B1[7]  += hi16(p1.w);
                B1[8]  += lo16(p3.x); B1[9]  += hi16(p3.x);
                B1[10] += lo16(p3.y); B1[11] += hi16(p3.y);
                B1[12] += lo16(p3.z); B1[13] += hi16(p3.z);
                B1[14] += lo16(p3.w); B1[15] += hi16(p3.w);
                j1 += 2;
            }
        }
        if (j0 < endr0) {                       // row0 leftover single edge -> even acc
            int sl = j0 - beg_all;
            int s0 = (sl < CSR_CAP) ? lcsr[sl] : csr[j0];
            const u16* pa = Hin + (size_t)s0 * EMB + gl * 16;
            uint4 q0 = *(const uint4*)pa, q2 = *(const uint4*)(pa + 8);
            A0[0]  += lo16(q0.x); A0[1]  += hi16(q0.x);
            A0[2]  += lo16(q0.y); A0[3]  += hi16(q0.y);
            A0[4]  += lo16(q0.z); A0[5]  += hi16(q0.z);
            A0[6]  += lo16(q0.w); A0[7]  += hi16(q0.w);
            A0[8]  += lo16(q2.x); A0[9]  += hi16(q2.x);
            A0[10] += lo16(q2.y); A0[11] += hi16(q2.y);
            A0[12] += lo16(q2.z); A0[13] += hi16(q2.z);
            A0[14] += lo16(q2.w); A0[15] += hi16(q2.w);
        }
        if (j1 < endr1) {                       // row1 leftover single edge -> even acc
            int sl = j1 - beg_all;
            int s0 = (sl < CSR_CAP) ? lcsr[sl] : csr[j1];
            const u16* pa = Hin + (size_t)s0 * EMB + gl * 16;
            uint4 p0 = *(const uint4*)pa, p2 = *(const uint4*)(pa + 8);
            B0[0]  += lo16(p0.x); B0[1]  += hi16(p0.x);
            B0[2]  += lo16(p0.y); B0[3]  += hi16(p0.y);
            B0[4]  += lo16(p0.z); B0[5]  += hi16(p0.z);
            B0[6]  += lo16(p0.w); B0[7]  += hi16(p0.w);
            B0[8]  += lo16(p2.x); B0[9]  += hi16(p2.x);
            B0[10] += lo16(p2.y); B0[11] += hi16(p2.y);
            B0[12] += lo16(p2.z); B0[13] += hi16(p2.z);
            B0[14] += lo16(p2.w); B0[15] += hi16(p2.w);
        }
        // lane gl covers cols [16gl,16gl+16): slice = gl>>2, k-groups 2gl&7 and (2gl&7)+1
        const int kg0 = (2 * gl) & 7;
        {
            uint4 o0, o1;
            o0.x = (u32)f2bf(A0[0]  + A1[0])  | ((u32)f2bf(A0[1]  + A1[1])  << 16);
            o0.y = (u32)f2bf(A0[2]  + A1[2])  | ((u32)f2bf(A0[3]  + A1[3])  << 16);
            o0.z = (u32)f2bf(A0[4]  + A1[4])  | ((u32)f2bf(A0[5]  + A1[5])  << 16);
            o0.w = (u32)f2bf(A0[6]  + A1[6])  | ((u32)f2bf(A0[7]  + A1[7])  << 16);
            o1.x = (u32)f2bf(A0[8]  + A1[8])  | ((u32)f2bf(A0[9]  + A1[9])  << 16);
            o1.y = (u32)f2bf(A0[10] + A1[10]) | ((u32)f2bf(A0[11] + A1[11]) << 16);
            o1.z = (u32)f2bf(A0[12] + A1[12]) | ((u32)f2bf(A0[13] + A1[13]) << 16);
            o1.w = (u32)f2bf(A0[14] + A1[14]) | ((u32)f2bf(A0[15] + A1[15]) << 16);
            u16* base = &aggA[(gl >> 2) * 4096 + r0 * 64];
            *(uint4*)(base + (kg0 ^ (r0 & 7)) * 8) = o0;
            *(uint4*)(base + ((kg0 + 1) ^ (r0 & 7)) * 8) = o1;
        }
        {
            uint4 o0, o1;
            o0.x = (u32)f2bf(B0[0]  + B1[0])  | ((u32)f2bf(B0[1]  + B1[1])  << 16);
            o0.y = (u32)f2bf(B0[2]  + B1[2])  | ((u32)f2bf(B0[3]  + B1[3])  << 16);
            o0.z = (u32)f2bf(B0[4]  + B1[4])  | ((u32)f2bf(B0[5]  + B1[5])  << 16);
            o0.w = (u32)f2bf(B0[6]  + B1[6])  | ((u32)f2bf(B0[7]  + B1[7])  << 16);
            o1.x = (u32)f2bf(B0[8]  + B1[8])  | ((u32)f2bf(B0[9]  + B1[9])  << 16);
            o1.y = (u32)f2bf(B0[10] + B1[10]) | ((u32)f2bf(B0[11] + B1[11]) << 16);
            o1.z = (u32)f2bf(B0[12] + B1[12]) | ((u32)f2bf(B0[13] + B1[13]) << 16);
            o1.w = (u32)f2bf(B0[14] + B1[14]) | ((u32)f2bf(B0[15] + B1[15]) << 16);
            u16* base = &aggA[(gl >> 2) * 4096 + r1 * 64];
            *(uint4*)(base + (kg0 ^ (r1 & 7)) * 8) = o0;
            *(uint4*)(base + ((kg0 + 1) ^ (r1 & 7)) * 8) = o1;
        }
    }
    asm volatile("s_waitcnt lgkmcnt(0)\n\ts_barrier" ::: "memory");

    // ---- phase 2: K-loop ----
    f32x4 acc[2][4] = {};
    #pragma unroll
    for (int s = 0; s < 8; ++s) {
        if (s > 0) stageB(s);
        if (s >= 1 && s <= 4) stageH(s + 3);   // h(4..7) -> slice s-1 (freed at iter s-1)
        if (s >= 1 && s <= 4) asm volatile("s_waitcnt vmcnt(1)\n\ts_barrier" ::: "memory");
        else                  asm volatile("s_waitcnt vmcnt(0)\n\ts_barrier" ::: "memory");

        const u16* la = aggA + (s & 3) * 4096;
        #pragma unroll
        for (int kk = 0; kk < 2; ++kk) {
            const int g = (((kk * 4 + quad) ^ (l16 & 7)) * 8);
            bf16x8 af[2], bfr[4];
            #pragma unroll
            for (int mt = 0; mt < 2; ++mt)
                af[mt] = *(const bf16x8*)&la[(wrow * 32 + mt * 16 + l16) * 64 + g];
            #pragma unroll
            for (int nt = 0; nt < 4; ++nt)
                bfr[nt] = *(const bf16x8*)&lB[(wcol * 64 + nt * 16 + l16) * 64 + g];
            #pragma unroll
            for (int mt = 0; mt < 2; ++mt)
                #pragma unroll
                for (int nt = 0; nt < 4; ++nt)
                    acc[mt][nt] = __builtin_amdgcn_mfma_f32_16x16x32_bf16(af[mt], bfr[nt], acc[mt][nt], 0, 0, 0);
        }
        asm volatile("s_waitcnt lgkmcnt(0)\n\ts_barrier" ::: "memory");
    }

    // -------- epilogue: bias + relu + residual(LDS) + LN --------
    // aggA slices 0..3 still hold the staged self-rows Hin[m0+r][0..256) (swizzled):
    // col = wcol*64 + c  ->  slice wcol, u16 index r*64 + ((c>>3)^(r&7))*8 + (c&7)
    if (tid < 64) { s_sum[tid] = 0.f; s_sq[tid] = 0.f; }
    __syncthreads();

    const int cb = wcol * 64;
    float blv[4], gv[4], bv[4];
    #pragma unroll
    for (int nt = 0; nt < 4; ++nt) {
        int col = cb + nt * 16 + l16;
        blv[nt] = bias[col]; gv[nt] = gam[col]; bv[nt] = bet[col];
    }

    #pragma unroll
    for (int mt = 0; mt < 2; ++mt) {
        #pragma unroll
        for (int i = 0; i < 4; ++i) {
            int r = wrow * 32 + mt * 16 + quad * 4 + i;   // C/D: col=lane&15, row=quad*4+i (m89)
            float rs = 0.f, rq = 0.f;
            #pragma unroll
            for (int nt = 0; nt < 4; ++nt) {
                int c = nt * 16 + l16;
                float res = bf2f(aggA[wcol * 4096 + r * 64 + (((c >> 3) ^ (r & 7)) << 3) + (c & 7)]);
                float v = acc[mt][nt][i] + blv[nt];
                v = fmaxf(v, 0.f);
                v += res;                                  // residual from LDS
                acc[mt][nt][i] = v;
                rs += v; rq += v * v;
            }
            #pragma unroll
            for (int m = 1; m < 16; m <<= 1) { rs += __shfl_xor(rs, m); rq += __shfl_xor(rq, m); }
            if (l16 == 0) { atomicAdd(&s_sum[r], rs); atomicAdd(&s_sq[r], rq); }
        }
    }
    __syncthreads();

    #pragma unroll
    for (int mt = 0; mt < 2; ++mt) {
        #pragma unroll
        for (int i = 0; i < 4; ++i) {
            int r = wrow * 32 + mt * 16 + quad * 4 + i;
            int rowg = m0 + r;
            float mean = s_sum[r] * (1.f / 256.f);
            float var = s_sq[r] * (1.f / 256.f) - mean * mean;
            float rstd = rsqrtf(var + LN_EPS);
            #pragma unroll
            for (int nt = 0; nt < 4; ++nt) {
                int col = cb + nt * 16 + l16;
                float o = (acc[mt][nt][i] - mean) * rstd * gv[nt] + bv[nt];
                if (F32OUT) outf[(size_t)rowg * EMB + col] = o;
                else        outb[(size_t)rowg * EMB + col] = f2bf(o);
            }
        }
    }
}

extern "C" void kernel_launch(void* const* d_in, const int* in_sizes, int n_in,
                              void* d_out, int out_size, void* d_ws, size_t ws_size,
                              hipStream_t stream)
{
    const int* node_emb = (const int*)d_in[0];
    const int* pos      = (const int*)d_in[1];
    const int* edge     = (const int*)d_in[2];
    const float* node_tab = (const float*)d_in[3];
    const float* pos_tab  = (const float*)d_in[4];
    const float* g_emb    = (const float*)d_in[5];
    const float* b_emb    = (const float*)d_in[6];
    const float* Wl0 = (const float*)d_in[7];
    const float* bl0 = (const float*)d_in[8];
    const float* Wr0 = (const float*)d_in[9];
    const float* g0  = (const float*)d_in[10];
    const float* b0  = (const float*)d_in[11];
    const float* Wl1 = (const float*)d_in[12];
    const float* bl1 = (const float*)d_in[13];
    const float* Wr1 = (const float*)d_in[14];
    const float* g1  = (const float*)d_in[15];
    const float* b1  = (const float*)d_in[16];

    char* w = (char*)d_ws;
    auto alloc = [&](size_t bytes) { char* p = w; w += (bytes + 255) & ~(size_t)255; return p; };
    u16* h0       = (u16*)alloc((size_t)N_NODES * EMB * 2);  // 134 MB (embed output)
    u16* h1       = (u16*)alloc((size_t)N_NODES * EMB * 2);  // 134 MB (layer-0 output)
    u16* wbf      = (u16*)alloc((size_t)4 * 65536 * 2);      // bf16 [Wl0|Wr0|Wl1|Wr1]
    int* deg      = (int*)alloc((size_t)N_NODES * 4);
    int* incl     = (int*)alloc((size_t)N_NODES * 4);
    int* rowstart = (int*)alloc((size_t)(N_NODES + 1) * 4);
    int* cursor   = (int*)alloc((size_t)N_NODES * 4);
    int* csr      = (int*)alloc((size_t)N_EDGES * 4);
    int* bsum     = (int*)alloc(256 * 4);
    int* boff     = (int*)alloc(256 * 4);

    float* outf = (float*)d_out;   // reference output dtype is float32

    const int* srcv = edge;
    const int* dstv = edge + N_EDGES;

    hipMemsetAsync(deg, 0, (size_t)N_NODES * 4, stream);
    convert_w_kernel<<<256, 256, 0, stream>>>(Wl0, Wr0, Wl1, Wr1, wbf);
    embed_ln_kernel<<<N_NODES / 4, 256, 0, stream>>>(node_emb, pos, node_tab, pos_tab, g_emb, b_emb, h0);
    hist_kernel<<<N_EDGES / 256, 256, 0, stream>>>(dstv, deg);
    scan1_kernel<<<N_NODES / 1024, 1024, 0, stream>>>(deg, incl, bsum);
    scan2_kernel<<<1, 256, 0, stream>>>(bsum, boff);
    scan3_kernel<<<N_NODES / 256, 256, 0, stream>>>(incl, deg, boff, rowstart, cursor);
    scatter_kernel<<<N_EDGES / 256, 256, 0, stream>>>(srcv, dstv, cursor, csr);

    // layer 0: gather(h0) + gemm -> h1   (NOT in place: other blocks gather our rows)
    gemm_fused_kernel<false><<<N_NODES / 64, 512, 0, stream>>>(
        h0, rowstart, csr, wbf, wbf + 65536, bl0, g0, b0, h1, nullptr);
    // layer 1: gather(h1) + gemm -> d_out (fp32)
    gemm_fused_kernel<true><<<N_NODES / 64, 512, 0, stream>>>(
        h1, rowstart, csr, wbf + 131072, wbf + 196608, bl1, g1, b1, nullptr, outf);
}

// Round 5
// 778.470 us; speedup vs baseline: 1.0538x; 1.0538x over previous
//
#include <hip/hip_runtime.h>
#include <hip/hip_bf16.h>
#include <stdint.h>

#define N_NODES 262144
#define N_EDGES 524288
#define EMB 256
#define LN_EPS 1e-5f
#define CSR_CAP 1024

typedef unsigned short u16;
typedef unsigned int u32;
typedef __bf16 bf16_t;
typedef __bf16 bf16x8 __attribute__((ext_vector_type(8)));
typedef float f32x4 __attribute__((ext_vector_type(4)));

__device__ __forceinline__ u16 f2bf(float f) {
    u32 u = __float_as_uint(f);
    u32 r = u + 0x7fffu + ((u >> 16) & 1u);
    return (u16)(r >> 16);
}
__device__ __forceinline__ float bf2f(u16 b) { return __uint_as_float(((u32)b) << 16); }
__device__ __forceinline__ float lo16(u32 x) { return __uint_as_float(x << 16); }
__device__ __forceinline__ float hi16(u32 x) { return __uint_as_float(x & 0xffff0000u); }

__device__ __forceinline__ void async_copy16(void* lds, const void* g) {
    __builtin_amdgcn_global_load_lds(
        (const __attribute__((address_space(1))) u32*)g,
        (__attribute__((address_space(3))) u32*)lds, 16, 0, 0);
}

// ---------- convert 4 weight matrices fp32 -> bf16 into ws ----------
__global__ __launch_bounds__(256) void convert_w_kernel(
    const float* __restrict__ a, const float* __restrict__ b,
    const float* __restrict__ c, const float* __restrict__ d,
    u16* __restrict__ out)
{
    int seg = blockIdx.x >> 6;       // 0..3
    int blk = blockIdx.x & 63;       // 0..63
    const float* src = (seg == 0) ? a : (seg == 1) ? b : (seg == 2) ? c : d;
    int off = blk * 1024 + threadIdx.x * 4;
    float4 v = *(const float4*)(src + off);
    uint2 o;
    o.x = (u32)f2bf(v.x) | ((u32)f2bf(v.y) << 16);
    o.y = (u32)f2bf(v.z) | ((u32)f2bf(v.w) << 16);
    *(uint2*)(out + seg * 65536 + off) = o;
}

// ---------- embed + layernorm: one wave per row (fp32 inputs -> bf16 h0) ----------
__global__ __launch_bounds__(256) void embed_ln_kernel(
    const int* __restrict__ node_emb, const int* __restrict__ pos,
    const float* __restrict__ node_tab, const float* __restrict__ pos_tab,
    const float* __restrict__ g_emb, const float* __restrict__ b_emb,
    u16* __restrict__ h0)
{
    const int wid = threadIdx.x >> 6, lane = threadIdx.x & 63;
    const int row = blockIdx.x * 4 + wid;
    const int idx = node_emb[row];
    const int p = pos[row];
    float4 ra = *(const float4*)(node_tab + (size_t)idx * EMB + lane * 4);
    float4 rb = *(const float4*)(pos_tab + (size_t)p * EMB + lane * 4);
    float v0 = ra.x * 16.f + rb.x;
    float v1 = ra.y * 16.f + rb.y;
    float v2 = ra.z * 16.f + rb.z;
    float v3 = ra.w * 16.f + rb.w;
    float s = v0 + v1 + v2 + v3;
    float sq = v0 * v0 + v1 * v1 + v2 * v2 + v3 * v3;
    #pragma unroll
    for (int m = 1; m < 64; m <<= 1) { s += __shfl_xor(s, m); sq += __shfl_xor(sq, m); }
    float mean = s * (1.f / 256.f);
    float var = sq * (1.f / 256.f) - mean * mean;
    float rstd = rsqrtf(var + LN_EPS);
    float4 rg = *(const float4*)(g_emb + lane * 4);
    float4 rbt = *(const float4*)(b_emb + lane * 4);
    float o0 = (v0 - mean) * rstd * rg.x + rbt.x;
    float o1 = (v1 - mean) * rstd * rg.y + rbt.y;
    float o2 = (v2 - mean) * rstd * rg.z + rbt.z;
    float o3 = (v3 - mean) * rstd * rg.w + rbt.w;
    uint2 out;
    out.x = (u32)f2bf(o0) | ((u32)f2bf(o1) << 16);
    out.y = (u32)f2bf(o2) | ((u32)f2bf(o3) << 16);
    *(uint2*)(h0 + (size_t)row * EMB + lane * 4) = out;
}

// ---------- CSR build ----------
__global__ __launch_bounds__(256) void hist_kernel(const int* __restrict__ dst, int* __restrict__ deg) {
    int e = blockIdx.x * 256 + threadIdx.x;
    atomicAdd(&deg[dst[e]], 1);
}

__global__ __launch_bounds__(1024) void scan1_kernel(const int* __restrict__ deg,
                                                     int* __restrict__ incl, int* __restrict__ bsum) {
    __shared__ int tmp[1024];
    int t = threadIdx.x, g = blockIdx.x * 1024 + t;
    tmp[t] = deg[g];
    __syncthreads();
    for (int off = 1; off < 1024; off <<= 1) {
        int x = (t >= off) ? tmp[t - off] : 0;
        __syncthreads();
        tmp[t] += x;
        __syncthreads();
    }
    incl[g] = tmp[t];
    if (t == 1023) bsum[blockIdx.x] = tmp[t];
}

__global__ __launch_bounds__(256) void scan2_kernel(const int* __restrict__ bsum, int* __restrict__ boff) {
    __shared__ int tmp[256];
    int t = threadIdx.x;
    int own = bsum[t];
    tmp[t] = own;
    __syncthreads();
    for (int off = 1; off < 256; off <<= 1) {
        int x = (t >= off) ? tmp[t - off] : 0;
        __syncthreads();
        tmp[t] += x;
        __syncthreads();
    }
    boff[t] = tmp[t] - own;
}

__global__ __launch_bounds__(256) void scan3_kernel(const int* __restrict__ incl, const int* __restrict__ deg,
                                                    const int* __restrict__ boff,
                                                    int* __restrict__ rowstart, int* __restrict__ cursor) {
    int g = blockIdx.x * 256 + threadIdx.x;
    int v = incl[g] - deg[g] + boff[g >> 10];
    rowstart[g] = v;
    cursor[g] = v;
    if (g == N_NODES - 1) rowstart[N_NODES] = N_EDGES;   // sentinel
}

__global__ __launch_bounds__(256) void scatter_kernel(const int* __restrict__ src, const int* __restrict__ dst,
                                                      int* __restrict__ cursor, int* __restrict__ csr) {
    int e = blockIdx.x * 256 + threadIdx.x;
    int slot = atomicAdd(&cursor[dst[e]], 1);
    csr[slot] = src[e];
}

// ---------- fused gather + GEMM: relu([segsum(h)|h] @ [Wl|Wr]^T + bl) + h, then LayerNorm ----------
// v6 (this round):
//  - REVERT R4's dual-row gather interleave (it spilled: +40 MB scratch writes). Gather is
//    R3's proven 2-rows-serial / 16-lane-group form.
//  - B reg-staging pipeline (T14): bregs hold B(s) loaded during step s-1's MFMA; per step:
//    ds_write bregs->lB (implicit vmcnt wait = 1-step-old loads, hidden), load B(s+1)->bregs,
//    lgkmcnt(0)+barrier, MFMA. Removes the per-step same-step L2 wait (~300-500 cyc x 8).
//    The implicit wait-for-bregs also drains each stageH (>=3 steps old) exactly when its
//    slice is consumed -> no explicit vmcnt needed anywhere in the K-loop.
//  - Dedicated 8 KB hX slice: stageH(4) issues BEFORE the gather (~5K cyc lead); stageH(5..7)
//    issue at steps 1..3 into freed aggA slices 0..2 (4-step lead).
//  - Epilogue residual reads h from LDS (hX/slice0..2), bit-identical staged values.
template<bool F32OUT>
__global__ __launch_bounds__(512, 4) void gemm_fused_kernel(
    const u16* __restrict__ Hin,
    const int* __restrict__ rowstart, const int* __restrict__ csr,
    const u16* __restrict__ Wl, const u16* __restrict__ Wr,
    const float* __restrict__ bias, const float* __restrict__ gam, const float* __restrict__ bet,
    u16* __restrict__ outb, float* __restrict__ outf)
{
    __shared__ alignas(16) u16 aggA[4 * 64 * 64];  // 32 KB: [slice][row][64], swizzled
    __shared__ alignas(16) u16 hX[64 * 64];        // 8 KB: h k-chunk 0 (consumed at step 4)
    __shared__ alignas(16) u16 lB[256 * 64];       // 32 KB, single-buffered (reg-staged)
    __shared__ int ls_row[72];                     // rowstart[m0..m0+64]
    __shared__ int lcsr[CSR_CAP];                  // block's contiguous csr segment
    __shared__ float s_sum[64];
    __shared__ float s_sq[64];

    const int tid = threadIdx.x;
    const int wid = tid >> 6, lane = tid & 63;
    const int quad = lane >> 4, l16 = lane & 15;
    const int wrow = wid >> 2, wcol = wid & 3;
    const int m0 = blockIdx.x * 64;
    const int lsrc = ((lane & 7) ^ (lane >> 3)) * 8;   // inverse-swizzled source k-offset

    // ---- B panel reg-staging ----
    uint4 breg0, breg1, breg2, breg3;
    auto loadB = [&](int s) {
        const int k0 = s * 64;
        const u16* Bsrc = (k0 < 256) ? (Wl + k0) : (Wr + (k0 - 256));
        const int n0 = (wid * 4 + 0) * 8 + (lane >> 3);
        const int n1 = (wid * 4 + 1) * 8 + (lane >> 3);
        const int n2 = (wid * 4 + 2) * 8 + (lane >> 3);
        const int n3 = (wid * 4 + 3) * 8 + (lane >> 3);
        breg0 = *(const uint4*)(Bsrc + (size_t)n0 * EMB + lsrc);
        breg1 = *(const uint4*)(Bsrc + (size_t)n1 * EMB + lsrc);
        breg2 = *(const uint4*)(Bsrc + (size_t)n2 * EMB + lsrc);
        breg3 = *(const uint4*)(Bsrc + (size_t)n3 * EMB + lsrc);
    };
    auto writeB = [&]() {
        *(uint4*)((char*)lB + (wid * 4 + 0) * 1024 + lane * 16) = breg0;
        *(uint4*)((char*)lB + (wid * 4 + 1) * 1024 + lane * 16) = breg1;
        *(uint4*)((char*)lB + (wid * 4 + 2) * 1024 + lane * 16) = breg2;
        *(uint4*)((char*)lB + (wid * 4 + 3) * 1024 + lane * 16) = breg3;
    };
    auto stageH = [&](int t, u16* dst) {   // h self-tile for k-step t (4..7)
        int row = tid >> 3;                // 0..63
        int kg = (tid & 7) ^ (row & 7);
        async_copy16((char*)dst + tid * 16,
                     Hin + (size_t)(m0 + row) * EMB + (t - 4) * 64 + kg * 8);
    };

    loadB(0);            // B(0) -> regs, in flight during gather
    stageH(4, hX);       // h k-chunk 0 -> hX, in flight during gather (~5K cyc lead)

    // ---- phase 0: burst-load rowstart + csr segment into LDS ----
    const int beg_all = rowstart[m0];          // broadcast load
    const int end_all = rowstart[m0 + 64];     // broadcast load
    const int cnt = end_all - beg_all;
    if (tid < 65) ls_row[tid] = rowstart[m0 + tid];
    const int lim = (cnt < CSR_CAP) ? cnt : CSR_CAP;
    for (int e = tid; e < lim; e += 512) lcsr[e] = csr[beg_all + e];
    asm volatile("s_waitcnt lgkmcnt(0)\n\ts_barrier" ::: "memory");

    // ---- phase 1: gather segment-sum into aggA slices 0..3 (R3 structure) ----
    {
        const int grp = tid >> 4, gl = tid & 15;   // 32 groups x 16 lanes; lane covers 16 cols
        #pragma unroll 1
        for (int i = 0; i < 2; ++i) {
            const int r = grp * 2 + i;              // local row 0..63
            const int beg = ls_row[r];
            const int end = ls_row[r + 1];
            // dual accumulators preserve the even/odd edge summation order exactly
            float a0[16] = {}, a1[16] = {};
            int j = beg;
            for (; j + 1 < end; j += 2) {
                int sl = j - beg_all;
                int s0 = (sl < CSR_CAP) ? lcsr[sl] : csr[j];
                int s1 = (sl + 1 < CSR_CAP) ? lcsr[sl + 1] : csr[j + 1];
                const u16* p0 = Hin + (size_t)s0 * EMB + gl * 16;
                const u16* p1 = Hin + (size_t)s1 * EMB + gl * 16;
                uint4 q0 = *(const uint4*)p0, q2 = *(const uint4*)(p0 + 8);
                uint4 q1 = *(const uint4*)p1, q3 = *(const uint4*)(p1 + 8);
                a0[0]  += lo16(q0.x); a0[1]  += hi16(q0.x);
                a0[2]  += lo16(q0.y); a0[3]  += hi16(q0.y);
                a0[4]  += lo16(q0.z); a0[5]  += hi16(q0.z);
                a0[6]  += lo16(q0.w); a0[7]  += hi16(q0.w);
                a0[8]  += lo16(q2.x); a0[9]  += hi16(q2.x);
                a0[10] += lo16(q2.y); a0[11] += hi16(q2.y);
                a0[12] += lo16(q2.z); a0[13] += hi16(q2.z);
                a0[14] += lo16(q2.w); a0[15] += hi16(q2.w);
                a1[0]  += lo16(q1.x); a1[1]  += hi16(q1.x);
                a1[2]  += lo16(q1.y); a1[3]  += hi16(q1.y);
                a1[4]  += lo16(q1.z); a1[5]  += hi16(q1.z);
                a1[6]  += lo16(q1.w); a1[7]  += hi16(q1.w);
                a1[8]  += lo16(q3.x); a1[9]  += hi16(q3.x);
                a1[10] += lo16(q3.y); a1[11] += hi16(q3.y);
                a1[12] += lo16(q3.z); a1[13] += hi16(q3.z);
                a1[14] += lo16(q3.w); a1[15] += hi16(q3.w);
            }
            if (j < end) {
                int sl = j - beg_all;
                int s0 = (sl < CSR_CAP) ? lcsr[sl] : csr[j];
                const u16* p0 = Hin + (size_t)s0 * EMB + gl * 16;
                uint4 q0 = *(const uint4*)p0, q2 = *(const uint4*)(p0 + 8);
                a0[0]  += lo16(q0.x); a0[1]  += hi16(q0.x);
                a0[2]  += lo16(q0.y); a0[3]  += hi16(q0.y);
                a0[4]  += lo16(q0.z); a0[5]  += hi16(q0.z);
                a0[6]  += lo16(q0.w); a0[7]  += hi16(q0.w);
                a0[8]  += lo16(q2.x); a0[9]  += hi16(q2.x);
                a0[10] += lo16(q2.y); a0[11] += hi16(q2.y);
                a0[12] += lo16(q2.z); a0[13] += hi16(q2.z);
                a0[14] += lo16(q2.w); a0[15] += hi16(q2.w);
            }
            // lane gl covers cols [16gl,16gl+16): slice = gl>>2, k-groups 2gl&7 and (2gl&7)+1
            uint4 o0, o1;
            o0.x = (u32)f2bf(a0[0]  + a1[0])  | ((u32)f2bf(a0[1]  + a1[1])  << 16);
            o0.y = (u32)f2bf(a0[2]  + a1[2])  | ((u32)f2bf(a0[3]  + a1[3])  << 16);
            o0.z = (u32)f2bf(a0[4]  + a1[4])  | ((u32)f2bf(a0[5]  + a1[5])  << 16);
            o0.w = (u32)f2bf(a0[6]  + a1[6])  | ((u32)f2bf(a0[7]  + a1[7])  << 16);
            o1.x = (u32)f2bf(a0[8]  + a1[8])  | ((u32)f2bf(a0[9]  + a1[9])  << 16);
            o1.y = (u32)f2bf(a0[10] + a1[10]) | ((u32)f2bf(a0[11] + a1[11]) << 16);
            o1.z = (u32)f2bf(a0[12] + a1[12]) | ((u32)f2bf(a0[13] + a1[13]) << 16);
            o1.w = (u32)f2bf(a0[14] + a1[14]) | ((u32)f2bf(a0[15] + a1[15]) << 16);
            int kg0 = (2 * gl) & 7;
            int cg0 = kg0 ^ (r & 7);
            int cg1 = (kg0 + 1) ^ (r & 7);
            u16* base = &aggA[(gl >> 2) * 4096 + r * 64];
            *(uint4*)(base + cg0 * 8) = o0;
            *(uint4*)(base + cg1 * 8) = o1;
        }
    }
    asm volatile("s_waitcnt lgkmcnt(0)\n\ts_barrier" ::: "memory");

    // ---- phase 2: K-loop (B reg-staged, no same-step VMEM waits) ----
    f32x4 acc[2][4] = {};
    #pragma unroll
    for (int s = 0; s < 8; ++s) {
        if (s >= 1 && s <= 3) stageH(s + 4, aggA + (s - 1) * 4096);  // 4-step lead
        writeB();                     // lB <= B(s); implicit vmcnt wait (1-step-old, hidden)
        if (s < 7) loadB(s + 1);      // B(s+1) -> regs, hides under this step's MFMA
        asm volatile("s_waitcnt lgkmcnt(0)\n\ts_barrier" ::: "memory");

        const u16* la = (s < 4) ? (aggA + s * 4096)
                      : (s == 4) ? hX
                                 : (aggA + (s - 5) * 4096);
        #pragma unroll
        for (int kk = 0; kk < 2; ++kk) {
            const int g = (((kk * 4 + quad) ^ (l16 & 7)) * 8);
            bf16x8 af[2], bfr[4];
            #pragma unroll
            for (int mt = 0; mt < 2; ++mt)
                af[mt] = *(const bf16x8*)&la[(wrow * 32 + mt * 16 + l16) * 64 + g];
            #pragma unroll
            for (int nt = 0; nt < 4; ++nt)
                bfr[nt] = *(const bf16x8*)&lB[(wcol * 64 + nt * 16 + l16) * 64 + g];
            #pragma unroll
            for (int mt = 0; mt < 2; ++mt)
                #pragma unroll
                for (int nt = 0; nt < 4; ++nt)
                    acc[mt][nt] = __builtin_amdgcn_mfma_f32_16x16x32_bf16(af[mt], bfr[nt], acc[mt][nt], 0, 0, 0);
        }
        asm volatile("s_waitcnt lgkmcnt(0)\n\ts_barrier" ::: "memory");
    }

    // -------- epilogue: bias + relu + residual(LDS) + LN --------
    // h self-rows live in LDS: k-chunk 0 -> hX, chunks 1..3 -> aggA slices 0..2 (swizzled):
    // within chunk, col cc -> u16 index r*64 + ((cc>>3)^(r&7))*8 + (cc&7)
    if (tid < 64) { s_sum[tid] = 0.f; s_sq[tid] = 0.f; }
    __syncthreads();

    const u16* resbuf = (wcol == 0) ? hX : (aggA + (wcol - 1) * 4096);
    const int cb = wcol * 64;
    float blv[4], gv[4], bv[4];
    #pragma unroll
    for (int nt = 0; nt < 4; ++nt) {
        int col = cb + nt * 16 + l16;
        blv[nt] = bias[col]; gv[nt] = gam[col]; bv[nt] = bet[col];
    }

    #pragma unroll
    for (int mt = 0; mt < 2; ++mt) {
        #pragma unroll
        for (int i = 0; i < 4; ++i) {
            int r = wrow * 32 + mt * 16 + quad * 4 + i;   // C/D: col=lane&15, row=quad*4+i (m89)
            float rs = 0.f, rq = 0.f;
            #pragma unroll
            for (int nt = 0; nt < 4; ++nt) {
                int cc = nt * 16 + l16;
                float res = bf2f(resbuf[r * 64 + (((cc >> 3) ^ (r & 7)) << 3) + (cc & 7)]);
                float v = acc[mt][nt][i] + blv[nt];
                v = fmaxf(v, 0.f);
                v += res;                                  // residual from LDS
                acc[mt][nt][i] = v;
                rs += v; rq += v * v;
            }
            #pragma unroll
            for (int m = 1; m < 16; m <<= 1) { rs += __shfl_xor(rs, m); rq += __shfl_xor(rq, m); }
            if (l16 == 0) { atomicAdd(&s_sum[r], rs); atomicAdd(&s_sq[r], rq); }
        }
    }
    __syncthreads();

    #pragma unroll
    for (int mt = 0; mt < 2; ++mt) {
        #pragma unroll
        for (int i = 0; i < 4; ++i) {
            int r = wrow * 32 + mt * 16 + quad * 4 + i;
            int rowg = m0 + r;
            float mean = s_sum[r] * (1.f / 256.f);
            float var = s_sq[r] * (1.f / 256.f) - mean * mean;
            float rstd = rsqrtf(var + LN_EPS);
            #pragma unroll
            for (int nt = 0; nt < 4; ++nt) {
                int col = cb + nt * 16 + l16;
                float o = (acc[mt][nt][i] - mean) * rstd * gv[nt] + bv[nt];
                if (F32OUT) outf[(size_t)rowg * EMB + col] = o;
                else        outb[(size_t)rowg * EMB + col] = f2bf(o);
            }
        }
    }
}

extern "C" void kernel_launch(void* const* d_in, const int* in_sizes, int n_in,
                              void* d_out, int out_size, void* d_ws, size_t ws_size,
                              hipStream_t stream)
{
    const int* node_emb = (const int*)d_in[0];
    const int* pos      = (const int*)d_in[1];
    const int* edge     = (const int*)d_in[2];
    const float* node_tab = (const float*)d_in[3];
    const float* pos_tab  = (const float*)d_in[4];
    const float* g_emb    = (const float*)d_in[5];
    const float* b_emb    = (const float*)d_in[6];
    const float* Wl0 = (const float*)d_in[7];
    const float* bl0 = (const float*)d_in[8];
    const float* Wr0 = (const float*)d_in[9];
    const float* g0  = (const float*)d_in[10];
    const float* b0  = (const float*)d_in[11];
    const float* Wl1 = (const float*)d_in[12];
    const float* bl1 = (const float*)d_in[13];
    const float* Wr1 = (const float*)d_in[14];
    const float* g1  = (const float*)d_in[15];
    const float* b1  = (const float*)d_in[16];

    char* w = (char*)d_ws;
    auto alloc = [&](size_t bytes) { char* p = w; w += (bytes + 255) & ~(size_t)255; return p; };
    u16* h0       = (u16*)alloc((size_t)N_NODES * EMB * 2);  // 134 MB (embed output)
    u16* h1       = (u16*)alloc((size_t)N_NODES * EMB * 2);  // 134 MB (layer-0 output)
    u16* wbf      = (u16*)alloc((size_t)4 * 65536 * 2);      // bf16 [Wl0|Wr0|Wl1|Wr1]
    int* deg      = (int*)alloc((size_t)N_NODES * 4);
    int* incl     = (int*)alloc((size_t)N_NODES * 4);
    int* rowstart = (int*)alloc((size_t)(N_NODES + 1) * 4);
    int* cursor   = (int*)alloc((size_t)N_NODES * 4);
    int* csr      = (int*)alloc((size_t)N_EDGES * 4);
    int* bsum     = (int*)alloc(256 * 4);
    int* boff     = (int*)alloc(256 * 4);

    float* outf = (float*)d_out;   // reference output dtype is float32

    const int* srcv = edge;
    const int* dstv = edge + N_EDGES;

    hipMemsetAsync(deg, 0, (size_t)N_NODES * 4, stream);
    convert_w_kernel<<<256, 256, 0, stream>>>(Wl0, Wr0, Wl1, Wr1, wbf);
    embed_ln_kernel<<<N_NODES / 4, 256, 0, stream>>>(node_emb, pos, node_tab, pos_tab, g_emb, b_emb, h0);
    hist_kernel<<<N_EDGES / 256, 256, 0, stream>>>(dstv, deg);
    scan1_kernel<<<N_NODES / 1024, 1024, 0, stream>>>(deg, incl, bsum);
    scan2_kernel<<<1, 256, 0, stream>>>(bsum, boff);
    scan3_kernel<<<N_NODES / 256, 256, 0, stream>>>(incl, deg, boff, rowstart, cursor);
    scatter_kernel<<<N_EDGES / 256, 256, 0, stream>>>(srcv, dstv, cursor, csr);

    // layer 0: gather(h0) + gemm -> h1   (NOT in place: other blocks gather our rows)
    gemm_fused_kernel<false><<<N_NODES / 64, 512, 0, stream>>>(
        h0, rowstart, csr, wbf, wbf + 65536, bl0, g0, b0, h1, nullptr);
    // layer 1: gather(h1) + gemm -> d_out (fp32)
    gemm_fused_kernel<true><<<N_NODES / 64, 512, 0, stream>>>(
        h1, rowstart, csr, wbf + 131072, wbf + 196608, bl1, g1, b1, nullptr, outf);
}